// Round 3
// baseline (541.438 us; speedup 1.0000x reference)
//
#include <hip/hip_runtime.h>

#define NTH 256
#define N_NODES 2048

// Table layout in d_ws (floats):
//   l3: [0 .. 165*12)   record t: [ b30 s0..2 | b31 s0p0..s2p2 ]  (symmetrized)
//   l2: [1980 .. +45*8) record t: [ b20 s0..1 | b21 s0p0..s1p2 ]
//   l1: [2340 .. +9*4)  record a: [ b10 | b11 p0..2 ]
#define L2_OFF 1980
#define L1_OFF 2340

__global__ void mace_build_tables(
    const float* __restrict__ b10, const float* __restrict__ b11,
    const float* __restrict__ b20, const float* __restrict__ b21,
    const float* __restrict__ b30, const float* __restrict__ b31,
    float* __restrict__ tab)
{
    const int tid = threadIdx.x;
    if (tid < 165) {
        int i = 0, j = 0, k = 0;
        {
            int c = 0;
            for (int ii = 0; ii < 9; ii++)
                for (int jj = ii; jj < 9; jj++)
                    for (int kk = jj; kk < 9; kk++) {
                        if (c == tid) { i = ii; j = jj; k = kk; }
                        c++;
                    }
        }
        float s[12];
        #pragma unroll
        for (int q = 0; q < 12; q++) s[q] = 0.f;
        auto add3 = [&](int a, int b, int c2) {
            int o30 = ((a * 9 + b) * 9 + c2) * 3;   // b30: (9,9,9,3,1)
            int o31 = o30 * 3;                      // b31: (9,9,9,3,3)
            #pragma unroll
            for (int q = 0; q < 3; q++) s[q] += b30[o30 + q];
            #pragma unroll
            for (int q = 0; q < 9; q++) s[3 + q] += b31[o31 + q];
        };
        if (i == j && j == k) { add3(i, j, k); }
        else if (i == j)      { add3(i, i, k); add3(i, k, i); add3(k, i, i); }
        else if (j == k)      { add3(i, j, j); add3(j, i, j); add3(j, j, i); }
        else { add3(i,j,k); add3(i,k,j); add3(j,i,k); add3(j,k,i); add3(k,i,j); add3(k,j,i); }
        #pragma unroll
        for (int q = 0; q < 12; q++) tab[tid * 12 + q] = s[q];
    } else if (tid < 210) {
        int t = tid - 165;
        int i = 0, j = 0;
        {
            int c = 0;
            for (int ii = 0; ii < 9; ii++)
                for (int jj = ii; jj < 9; jj++) {
                    if (c == t) { i = ii; j = jj; }
                    c++;
                }
        }
        float s[8];
        #pragma unroll
        for (int q = 0; q < 8; q++) s[q] = 0.f;
        auto add2 = [&](int a, int b) {
            int o20 = (a * 9 + b) * 2;   // b20: (9,9,2,1)
            int o21 = o20 * 3;           // b21: (9,9,2,3)
            #pragma unroll
            for (int q = 0; q < 2; q++) s[q] += b20[o20 + q];
            #pragma unroll
            for (int q = 0; q < 6; q++) s[2 + q] += b21[o21 + q];
        };
        if (i == j) add2(i, i); else { add2(i, j); add2(j, i); }
        #pragma unroll
        for (int q = 0; q < 8; q++) tab[L2_OFF + t * 8 + q] = s[q];
    } else if (tid < 219) {
        int a = tid - 210;
        tab[L1_OFF + a * 4 + 0] = b10[a];                 // b10: (9,1,1)
        #pragma unroll
        for (int p = 0; p < 3; p++) tab[L1_OFF + a * 4 + 1 + p] = b11[a * 3 + p];  // b11: (9,1,3)
    }
}

// One thread per (node, mul). Wave = 64 consecutive muls of one node
// (node, species wave-uniform; all global accesses coalesced).
// Coefficient table addresses are wave-uniform + compile-time offsets after
// full unroll -> scalar-load / L1-broadcast friendly.
__global__ __launch_bounds__(NTH, 4) void mace_main(
    const float* __restrict__ nf, const int* __restrict__ spec,
    const float* __restrict__ tab,
    const float* __restrict__ w10, const float* __restrict__ w11,
    const float* __restrict__ w20, const float* __restrict__ w21,
    const float* __restrict__ w30, const float* __restrict__ w31,
    float* __restrict__ out)
{
    const int g    = blockIdx.x * NTH + threadIdx.x;   // 262144 threads
    const int node = g >> 7;                           // 128 muls per node
    const int m    = g & 127;

    const float* nfp = nf + node * 1152;
    float f[9];
    f[0] = nfp[m];                                         // 0e block
    #pragma unroll
    for (int j = 0; j < 3; j++) f[1 + j] = nfp[128 + m * 3 + j];   // 1o
    #pragma unroll
    for (int j = 0; j < 5; j++) f[4 + j] = nfp[512 + m * 5 + j];   // 2e

    const int z = spec[node];                              // wave-uniform

    // weights up-front (12 coalesced loads, overlap with compute)
    float w30v[3], w31v[3], w20v[2], w21v[2];
    #pragma unroll
    for (int s = 0; s < 3; s++) {
        w30v[s] = w30[(z * 3 + s) * 128 + m];
        w31v[s] = w31[(z * 3 + s) * 128 + m];
    }
    #pragma unroll
    for (int s = 0; s < 2; s++) {
        w20v[s] = w20[(z * 2 + s) * 128 + m];
        w21v[s] = w21[(z * 2 + s) * 128 + m];
    }
    const float w10v = w10[z * 128 + m];
    const float w11v = w11[z * 128 + m];

    const float* l3 = tab;
    const float* l2 = tab + L2_OFF;
    const float* l1 = tab + L1_OFF;

    float acc[4] = {0.f, 0.f, 0.f, 0.f};

    // ---- nu = 3 : 165 symmetric monomials, fully unrolled ----
    {
        float t3[12];
        #pragma unroll
        for (int q = 0; q < 12; q++) t3[q] = 0.f;

        int t = 0;
        #pragma unroll
        for (int i = 0; i < 9; i++) {
            #pragma unroll
            for (int j = i; j < 9; j++) {
                const float fij = f[i] * f[j];
                #pragma unroll
                for (int k = j; k < 9; k++) {
                    const float m3 = fij * f[k];
                    const float* c = &l3[t * 12];
                    #pragma unroll
                    for (int q = 0; q < 12; q++) t3[q] = fmaf(c[q], m3, t3[q]);
                    t++;
                }
            }
        }
        #pragma unroll
        for (int s = 0; s < 3; s++) {
            acc[0] = fmaf(w30v[s], t3[s], acc[0]);
            #pragma unroll
            for (int p = 0; p < 3; p++)
                acc[1 + p] = fmaf(w31v[s], t3[3 + s * 3 + p], acc[1 + p]);
        }
    }

    // ---- nu = 2 : 45 monomials ----
    {
        float t2[8];
        #pragma unroll
        for (int q = 0; q < 8; q++) t2[q] = 0.f;

        int t = 0;
        #pragma unroll
        for (int i = 0; i < 9; i++) {
            #pragma unroll
            for (int j = i; j < 9; j++) {
                const float m2 = f[i] * f[j];
                const float* c = &l2[t * 8];
                #pragma unroll
                for (int q = 0; q < 8; q++) t2[q] = fmaf(c[q], m2, t2[q]);
                t++;
            }
        }
        #pragma unroll
        for (int s = 0; s < 2; s++) {
            acc[0] = fmaf(w20v[s], t2[s], acc[0]);
            #pragma unroll
            for (int p = 0; p < 3; p++)
                acc[1 + p] = fmaf(w21v[s], t2[2 + s * 3 + p], acc[1 + p]);
        }
    }

    // ---- nu = 1 : 9 terms ----
    {
        float t1[4];
        #pragma unroll
        for (int q = 0; q < 4; q++) t1[q] = 0.f;
        #pragma unroll
        for (int a = 0; a < 9; a++) {
            const float* c = &l1[a * 4];
            #pragma unroll
            for (int q = 0; q < 4; q++) t1[q] = fmaf(c[q], f[a], t1[q]);
        }
        acc[0] = fmaf(w10v, t1[0], acc[0]);
        #pragma unroll
        for (int p = 0; p < 3; p++) acc[1 + p] = fmaf(w11v, t1[1 + p], acc[1 + p]);
    }

    // ---- store: out (n, 512) = [ (n,128) p=0 | (n,128,3) p=1..3 ] ----
    float* op = out + node * 512;
    op[m] = acc[0];
    #pragma unroll
    for (int p = 0; p < 3; p++) op[128 + m * 3 + p] = acc[1 + p];
}

extern "C" void kernel_launch(void* const* d_in, const int* in_sizes, int n_in,
                              void* d_out, int out_size, void* d_ws, size_t ws_size,
                              hipStream_t stream) {
    // setup_inputs() dict order is INTERLEAVED: node_feats, species,
    // b10, w10, b11, w11, b20, w20, b21, w21, b30, w30, b31, w31
    const float* nf  = (const float*)d_in[0];
    const int* spec  = (const int*)d_in[1];
    const float* b10 = (const float*)d_in[2];
    const float* w10 = (const float*)d_in[3];
    const float* b11 = (const float*)d_in[4];
    const float* w11 = (const float*)d_in[5];
    const float* b20 = (const float*)d_in[6];
    const float* w20 = (const float*)d_in[7];
    const float* b21 = (const float*)d_in[8];
    const float* w21 = (const float*)d_in[9];
    const float* b30 = (const float*)d_in[10];
    const float* w30 = (const float*)d_in[11];
    const float* b31 = (const float*)d_in[12];
    const float* w31 = (const float*)d_in[13];
    float* out = (float*)d_out;
    float* tab = (float*)d_ws;   // 2376 floats

    mace_build_tables<<<1, NTH, 0, stream>>>(b10, b11, b20, b21, b30, b31, tab);

    const int grid = (N_NODES * 128) / NTH;   // 1024 blocks
    mace_main<<<grid, NTH, 0, stream>>>(
        nf, spec, tab, w10, w11, w20, w21, w30, w31, out);
}

// Round 4
// 139.926 us; speedup vs baseline: 3.8695x; 3.8695x over previous
//
#include <hip/hip_runtime.h>

#define NTH 256
#define N_NODES 2048

// Table layout in d_ws (floats):
//   l3: [0 .. 165*16)      record t (stride 16, 12 used): [ b30 s0..2 | b31 s0p0..s2p2 ]
//   l2: [2640 .. +45*8)    record t (stride 8):           [ b20 s0..1 | b21 s0p0..s1p2 ]
//   l1: [3000 .. +9*4)     record a (stride 4):           [ b10 | b11 p0..2 ]
#define L3_STRIDE 16
#define L2_OFF 2640
#define L1_OFF 3000

__global__ void mace_build_tables(
    const float* __restrict__ b10, const float* __restrict__ b11,
    const float* __restrict__ b20, const float* __restrict__ b21,
    const float* __restrict__ b30, const float* __restrict__ b31,
    float* __restrict__ tab)
{
    const int tid = threadIdx.x;
    if (tid < 165) {
        int i = 0, j = 0, k = 0;
        {
            int c = 0;
            for (int ii = 0; ii < 9; ii++)
                for (int jj = ii; jj < 9; jj++)
                    for (int kk = jj; kk < 9; kk++) {
                        if (c == tid) { i = ii; j = jj; k = kk; }
                        c++;
                    }
        }
        float s[12];
        #pragma unroll
        for (int q = 0; q < 12; q++) s[q] = 0.f;
        auto add3 = [&](int a, int b, int c2) {
            int o30 = ((a * 9 + b) * 9 + c2) * 3;   // b30: (9,9,9,3,1)
            int o31 = o30 * 3;                      // b31: (9,9,9,3,3)
            #pragma unroll
            for (int q = 0; q < 3; q++) s[q] += b30[o30 + q];
            #pragma unroll
            for (int q = 0; q < 9; q++) s[3 + q] += b31[o31 + q];
        };
        if (i == j && j == k) { add3(i, j, k); }
        else if (i == j)      { add3(i, i, k); add3(i, k, i); add3(k, i, i); }
        else if (j == k)      { add3(i, j, j); add3(j, i, j); add3(j, j, i); }
        else { add3(i,j,k); add3(i,k,j); add3(j,i,k); add3(j,k,i); add3(k,i,j); add3(k,j,i); }
        #pragma unroll
        for (int q = 0; q < 12; q++) tab[tid * L3_STRIDE + q] = s[q];
        #pragma unroll
        for (int q = 12; q < 16; q++) tab[tid * L3_STRIDE + q] = 0.f;
    } else if (tid < 210) {
        int t = tid - 165;
        int i = 0, j = 0;
        {
            int c = 0;
            for (int ii = 0; ii < 9; ii++)
                for (int jj = ii; jj < 9; jj++) {
                    if (c == t) { i = ii; j = jj; }
                    c++;
                }
        }
        float s[8];
        #pragma unroll
        for (int q = 0; q < 8; q++) s[q] = 0.f;
        auto add2 = [&](int a, int b) {
            int o20 = (a * 9 + b) * 2;   // b20: (9,9,2,1)
            int o21 = o20 * 3;           // b21: (9,9,2,3)
            #pragma unroll
            for (int q = 0; q < 2; q++) s[q] += b20[o20 + q];
            #pragma unroll
            for (int q = 0; q < 6; q++) s[2 + q] += b21[o21 + q];
        };
        if (i == j) add2(i, i); else { add2(i, j); add2(j, i); }
        #pragma unroll
        for (int q = 0; q < 8; q++) tab[L2_OFF + t * 8 + q] = s[q];
    } else if (tid < 219) {
        int a = tid - 210;
        tab[L1_OFF + a * 4 + 0] = b10[a];                 // b10: (9,1,1)
        #pragma unroll
        for (int p = 0; p < 3; p++) tab[L1_OFF + a * 4 + 1 + p] = b11[a * 3 + p];  // b11: (9,1,3)
    }
}

// One thread per (node, mul). Wave = 64 consecutive muls of one node
// (node/species wave-uniform; all global accesses coalesced).
// Coefficient table indices are compile-time after full unroll and the base
// pointer is uniform -> compiler emits s_load (SGPR coefficients, no LDS,
// v_fma v,s,v,v). NOTE: __launch_bounds__(NTH,1) — R3's (NTH,4) capped VGPRs
// at 64 and caused a 1.2 GB scratch-spill catastrophe.
__global__ __launch_bounds__(NTH, 1) void mace_main(
    const float* __restrict__ nf, const int* __restrict__ spec,
    const float* __restrict__ tab,
    const float* __restrict__ w10, const float* __restrict__ w11,
    const float* __restrict__ w20, const float* __restrict__ w21,
    const float* __restrict__ w30, const float* __restrict__ w31,
    float* __restrict__ out)
{
    const int g    = blockIdx.x * NTH + threadIdx.x;   // 262144 threads
    const int node = g >> 7;                           // 128 muls per node
    const int m    = g & 127;

    const float* nfp = nf + node * 1152;
    float f[9];
    f[0] = nfp[m];                                         // 0e block
    #pragma unroll
    for (int j = 0; j < 3; j++) f[1 + j] = nfp[128 + m * 3 + j];   // 1o
    #pragma unroll
    for (int j = 0; j < 5; j++) f[4 + j] = nfp[512 + m * 5 + j];   // 2e

    const int z = spec[node];                              // wave-uniform

    // weights up-front (12 coalesced loads, overlap with compute)
    float w30v[3], w31v[3], w20v[2], w21v[2];
    #pragma unroll
    for (int s = 0; s < 3; s++) {
        w30v[s] = w30[(z * 3 + s) * 128 + m];
        w31v[s] = w31[(z * 3 + s) * 128 + m];
    }
    #pragma unroll
    for (int s = 0; s < 2; s++) {
        w20v[s] = w20[(z * 2 + s) * 128 + m];
        w21v[s] = w21[(z * 2 + s) * 128 + m];
    }
    const float w10v = w10[z * 128 + m];
    const float w11v = w11[z * 128 + m];

    const float* l2 = tab + L2_OFF;
    const float* l1 = tab + L1_OFF;

    float acc[4] = {0.f, 0.f, 0.f, 0.f};

    // ---- nu = 3 : 165 symmetric monomials, fully unrolled ----
    {
        float t3[12];
        #pragma unroll
        for (int q = 0; q < 12; q++) t3[q] = 0.f;

        int t = 0;
        #pragma unroll
        for (int i = 0; i < 9; i++) {
            #pragma unroll
            for (int j = i; j < 9; j++) {
                const float fij = f[i] * f[j];
                #pragma unroll
                for (int k = j; k < 9; k++) {
                    const float m3 = fij * f[k];
                    const float* c = &tab[t * L3_STRIDE];
                    #pragma unroll
                    for (int q = 0; q < 12; q++) t3[q] = fmaf(c[q], m3, t3[q]);
                    t++;
                }
            }
        }
        #pragma unroll
        for (int s = 0; s < 3; s++) {
            acc[0] = fmaf(w30v[s], t3[s], acc[0]);
            #pragma unroll
            for (int p = 0; p < 3; p++)
                acc[1 + p] = fmaf(w31v[s], t3[3 + s * 3 + p], acc[1 + p]);
        }
    }

    // ---- nu = 2 : 45 monomials ----
    {
        float t2[8];
        #pragma unroll
        for (int q = 0; q < 8; q++) t2[q] = 0.f;

        int t = 0;
        #pragma unroll
        for (int i = 0; i < 9; i++) {
            #pragma unroll
            for (int j = i; j < 9; j++) {
                const float m2 = f[i] * f[j];
                const float* c = &l2[t * 8];
                #pragma unroll
                for (int q = 0; q < 8; q++) t2[q] = fmaf(c[q], m2, t2[q]);
                t++;
            }
        }
        #pragma unroll
        for (int s = 0; s < 2; s++) {
            acc[0] = fmaf(w20v[s], t2[s], acc[0]);
            #pragma unroll
            for (int p = 0; p < 3; p++)
                acc[1 + p] = fmaf(w21v[s], t2[2 + s * 3 + p], acc[1 + p]);
        }
    }

    // ---- nu = 1 : 9 terms ----
    {
        float t1[4];
        #pragma unroll
        for (int q = 0; q < 4; q++) t1[q] = 0.f;
        #pragma unroll
        for (int a = 0; a < 9; a++) {
            const float* c = &l1[a * 4];
            #pragma unroll
            for (int q = 0; q < 4; q++) t1[q] = fmaf(c[q], f[a], t1[q]);
        }
        acc[0] = fmaf(w10v, t1[0], acc[0]);
        #pragma unroll
        for (int p = 0; p < 3; p++) acc[1 + p] = fmaf(w11v, t1[1 + p], acc[1 + p]);
    }

    // ---- store: out (n, 512) = [ (n,128) p=0 | (n,128,3) p=1..3 ] ----
    float* op = out + node * 512;
    op[m] = acc[0];
    #pragma unroll
    for (int p = 0; p < 3; p++) op[128 + m * 3 + p] = acc[1 + p];
}

extern "C" void kernel_launch(void* const* d_in, const int* in_sizes, int n_in,
                              void* d_out, int out_size, void* d_ws, size_t ws_size,
                              hipStream_t stream) {
    // setup_inputs() dict order is INTERLEAVED: node_feats, species,
    // b10, w10, b11, w11, b20, w20, b21, w21, b30, w30, b31, w31
    const float* nf  = (const float*)d_in[0];
    const int* spec  = (const int*)d_in[1];
    const float* b10 = (const float*)d_in[2];
    const float* w10 = (const float*)d_in[3];
    const float* b11 = (const float*)d_in[4];
    const float* w11 = (const float*)d_in[5];
    const float* b20 = (const float*)d_in[6];
    const float* w20 = (const float*)d_in[7];
    const float* b21 = (const float*)d_in[8];
    const float* w21 = (const float*)d_in[9];
    const float* b30 = (const float*)d_in[10];
    const float* w30 = (const float*)d_in[11];
    const float* b31 = (const float*)d_in[12];
    const float* w31 = (const float*)d_in[13];
    float* out = (float*)d_out;
    float* tab = (float*)d_ws;   // 3036 floats

    mace_build_tables<<<1, NTH, 0, stream>>>(b10, b11, b20, b21, b30, b31, tab);

    const int grid = (N_NODES * 128) / NTH;   // 1024 blocks
    mace_main<<<grid, NTH, 0, stream>>>(
        nf, spec, tab, w10, w11, w20, w21, w30, w31, out);
}